// Round 18
// baseline (66.427 us; speedup 1.0000x reference)
//
#include <hip/hip_runtime.h>

#define THREADS 256
#define PI_F 3.14159265358979323846f
#define RT2O2 0.70710678118654752440f

// Complex as native 2-float vector -> packed fp32 (v_pk_add/fma_f32).
typedef float cpx __attribute__((ext_vector_type(2)));

__device__ __forceinline__ cpx cmul(cpx a, cpx b) {
    cpx r = cpx{a.x, a.x} * b;
    return r + cpx{-a.y, a.y} * cpx{b.y, b.x};
}
__device__ __forceinline__ cpx mulni(cpx a) { return cpx{a.y, -a.x}; }   // * (-i)
__device__ __forceinline__ cpx mulpi(cpx a) { return cpx{-a.y, a.x}; }   // * (+i)

// XOR swizzle on cpx index (8B units): bits [3:1] ^= (bits[6:4]^bits[10:8]).
// Bit 0 untouched -> cpx-pair (float4) contiguity preserved.
__device__ __forceinline__ int SW(int i) { return i ^ ((((i >> 4) ^ (i >> 8)) & 7) << 1); }

__device__ __forceinline__ cpx ldb(const cpx* b, int i) { return b[SW(i)]; }
__device__ __forceinline__ void stb(cpx* b, int i, cpx v) { b[SW(i)] = v; }

// cos/sin(pi*s/16), cos/sin(pi*s/64) (epilogue) and cos/sin(pi*a/128)
// (stage-2 twiddle base W256^a), all compile-time folded.
constexpr float C16[16] = {
    1.f, 0.98078528040323044f, 0.92387953251128674f, 0.83146961230254524f,
    RT2O2, 0.55557023301960222f, 0.38268343236508978f, 0.19509032201612827f,
    0.f, -0.19509032201612827f, -0.38268343236508978f, -0.55557023301960222f,
    -RT2O2, -0.83146961230254524f, -0.92387953251128674f, -0.98078528040323044f};
constexpr float S16[16] = {
    0.f, 0.19509032201612827f, 0.38268343236508978f, 0.55557023301960222f,
    RT2O2, 0.83146961230254524f, 0.92387953251128674f, 0.98078528040323044f,
    1.f, 0.98078528040323044f, 0.92387953251128674f, 0.83146961230254524f,
    RT2O2, 0.55557023301960222f, 0.38268343236508978f, 0.19509032201612827f};
constexpr float C64[16] = {
    1.f, 0.99879545620517239f, 0.99518472667219693f, 0.98917650996478101f,
    0.98078528040323044f, 0.97003125319454397f, 0.95694033573220886f, 0.94154406518302081f,
    0.92387953251128674f, 0.90398929312344334f, 0.88192126434835503f, 0.85772861000027212f,
    0.83146961230254524f, 0.80320753148064494f, 0.77301045336273699f, 0.74095112535495911f};
constexpr float S64[16] = {
    0.f, 0.04906767432741801f, 0.09801714032956060f, 0.14673047445536175f,
    0.19509032201612827f, 0.24298017990326390f, 0.29028467725446233f, 0.33688985339222005f,
    0.38268343236508978f, 0.42755509343028208f, 0.47139673682599764f, 0.51410274419322166f,
    0.55557023301960222f, 0.59569930449243336f, 0.63439328416364549f, 0.67155895484701833f};
constexpr float C128[16] = {
    1.f, 0.99969881869620422f, 0.99879545620517239f, 0.99729045667869021f,
    0.99518472667219693f, 0.99247953459870997f, 0.98917650996478101f, 0.98527764238894122f,
    0.98078528040323044f, 0.97570213003852857f, 0.97003125319454397f, 0.96377606579543984f,
    0.95694033573220886f, 0.94952818059303667f, 0.94154406518302081f, 0.93299279883473885f};
constexpr float S128[16] = {
    0.f, 0.024541228522912288f, 0.049067674327418015f, 0.073564563599667426f,
    0.098017140329560602f, 0.12241067519921620f, 0.14673047445536175f, 0.17096188876030122f,
    0.19509032201612827f, 0.21910124015686980f, 0.24298017990326390f, 0.26671275747489837f,
    0.29028467725446233f, 0.31368174039889152f, 0.33688985339222005f, 0.35989503653498811f};

// In-place 16-point DFT, natural order in/out: z[s] = sum_n z[n] W16^{ns}
__device__ __forceinline__ void dft16(cpx* z) {
    cpx t[4][4];
#pragma unroll
    for (int n0 = 0; n0 < 4; ++n0) {
        cpx a = z[n0], b = z[4 + n0], c = z[8 + n0], d = z[12 + n0];
        cpx apc = a + c, amc = a - c, bpd = b + d, bmd = b - d;
        t[n0][0] = apc + bpd;
        t[n0][1] = amc + mulni(bmd);
        t[n0][2] = apc - bpd;
        t[n0][3] = amc + mulpi(bmd);
    }
    const cpx W1 = {0.92387953251128674f, -0.38268343236508978f};
    const cpx W2 = {RT2O2, -RT2O2};
    const cpx W3 = {0.38268343236508978f, -0.92387953251128674f};
    const cpx W6 = {-RT2O2, -RT2O2};
    const cpx W9 = {-0.92387953251128674f, 0.38268343236508978f};
    t[1][1] = cmul(t[1][1], W1); t[1][2] = cmul(t[1][2], W2); t[1][3] = cmul(t[1][3], W3);
    t[2][1] = cmul(t[2][1], W2); t[2][2] = mulni(t[2][2]);    t[2][3] = cmul(t[2][3], W6);
    t[3][1] = cmul(t[3][1], W3); t[3][2] = cmul(t[3][2], W6); t[3][3] = cmul(t[3][3], W9);
#pragma unroll
    for (int s0 = 0; s0 < 4; ++s0) {
        cpx a = t[0][s0], b = t[1][s0], c = t[2][s0], d = t[3][s0];
        cpx apc = a + c, amc = a - c, bpd = b + d, bmd = b - d;
        z[s0]      = apc + bpd;
        z[s0 + 4]  = amc + mulni(bmd);
        z[s0 + 8]  = apc - bpd;
        z[s0 + 12] = amc + mulpi(bmd);
    }
}

// Apply w1^s to BOTH rows' z[s]: powers tree computed ONCE (the dual-row
// sharing win — twiddle angles depend on t only, not the row).
__device__ __forceinline__ void twiddle16w2(cpx* a, cpx* b, cpx w1) {
    cpx w2 = cmul(w1, w1), w3 = cmul(w1, w2), w4 = cmul(w2, w2);
    cpx w5 = cmul(w1, w4), w6 = cmul(w2, w4), w7 = cmul(w3, w4), w8 = cmul(w4, w4);
    cpx w9 = cmul(w1, w8), w10 = cmul(w2, w8), w11 = cmul(w3, w8), w12 = cmul(w4, w8);
    cpx w13 = cmul(w5, w8), w14 = cmul(w6, w8), w15 = cmul(w7, w8);
    a[1] = cmul(a[1], w1);   b[1] = cmul(b[1], w1);
    a[2] = cmul(a[2], w2);   b[2] = cmul(b[2], w2);
    a[3] = cmul(a[3], w3);   b[3] = cmul(b[3], w3);
    a[4] = cmul(a[4], w4);   b[4] = cmul(b[4], w4);
    a[5] = cmul(a[5], w5);   b[5] = cmul(b[5], w5);
    a[6] = cmul(a[6], w6);   b[6] = cmul(b[6], w6);
    a[7] = cmul(a[7], w7);   b[7] = cmul(b[7], w7);
    a[8] = cmul(a[8], w8);   b[8] = cmul(b[8], w8);
    a[9] = cmul(a[9], w9);   b[9] = cmul(b[9], w9);
    a[10] = cmul(a[10], w10); b[10] = cmul(b[10], w10);
    a[11] = cmul(a[11], w11); b[11] = cmul(b[11], w11);
    a[12] = cmul(a[12], w12); b[12] = cmul(b[12], w12);
    a[13] = cmul(a[13], w13); b[13] = cmul(b[13], w13);
    a[14] = cmul(a[14], w14); b[14] = cmul(b[14], w14);
    a[15] = cmul(a[15], w15); b[15] = cmul(b[15], w15);
}

// TWO rows per block, both in the SAME thread (dual-row ILP + shared
// twiddle factors). Per row: R14 structure — DST-II via N/2=4096 complex
// FFT (radices 16,16,16), pair-folded epilogue, half stage-3 write-back.
//   v = Makhoul(sign*x); z[m] = v[2m] + i*v[2m+1]; Z = FFT_4096(z)
//   V[k] = Ze[k] + e^{-i pi k/4096} Zo[k]; out[8191-k] = Re(V[k] e^{-i pi k/16384})
// Sharing: sincos/power-trees/epilogue factors depend on t only -> computed
// once for both rows. Barriers per row halve. 64 KiB LDS -> 2 blocks/CU;
// __launch_bounds__(256,2) budgets 256 VGPR (no spill possible at ~150 live).
__global__ __launch_bounds__(THREADS, 2) void dst_fft_kernel(const float* __restrict__ x,
                                                             float* __restrict__ out) {
    __shared__ __align__(16) cpx bufA[4096];  // 32 KiB (row a)
    __shared__ __align__(16) cpx bufB[4096];  // 32 KiB (row b)

    const int row = 2 * blockIdx.x;
    const float* __restrict__ xa = x + (size_t)row * 8192;
    const float* __restrict__ xb = xa + 8192;
    float* __restrict__ ya = out + (size_t)row * 8192;
    float* __restrict__ yb = ya + 8192;
    const int t = threadIdx.x;

    cpx za[16], zb[16];

    // ---- load both rows in stage-1 butterfly order: m = t + 256u ----
#pragma unroll
    for (int u = 0; u < 8; ++u) {
        float4 fa = *reinterpret_cast<const float4*>(xa + 4 * t + 1024 * u);
        float4 fb = *reinterpret_cast<const float4*>(xb + 4 * t + 1024 * u);
        za[u] = {fa.x, fa.z};
        zb[u] = {fb.x, fb.z};
    }
#pragma unroll
    for (int u = 8; u < 16; ++u) {
        float4 fa = *reinterpret_cast<const float4*>(xa + (16380 - 4 * t - 1024 * u));
        float4 fb = *reinterpret_cast<const float4*>(xb + (16380 - 4 * t - 1024 * u));
        za[u] = {-fa.w, -fa.y};
        zb[u] = {-fb.w, -fb.y};
    }

    // ---- stage 1: radix-16, stride 256 (shared twiddle tree) ----
    dft16(za);
    dft16(zb);
    {
        float s_, c_;
        __sincosf((-2.0f * PI_F / 4096.0f) * (float)t, &s_, &c_);
        twiddle16w2(za, zb, cpx{c_, s_});
    }
#pragma unroll
    for (int s = 0; s < 16; ++s) {
        stb(bufA, t + (s << 8), za[s]);
        stb(bufB, t + (s << 8), zb[s]);
    }
    __syncthreads();

    // ---- stage 2: stride 16, in-place per thread (shared twiddle tree) ----
    const int base2 = ((t >> 4) << 8) + (t & 15);
#pragma unroll
    for (int s = 0; s < 16; ++s) {
        za[s] = ldb(bufA, base2 + (s << 4));
        zb[s] = ldb(bufB, base2 + (s << 4));
    }
    dft16(za);
    dft16(zb);
    twiddle16w2(za, zb, cpx{C128[t & 15], -S128[t & 15]});  // W256^{(t&15)}
#pragma unroll
    for (int s = 0; s < 16; ++s) {
        stb(bufA, base2 + (s << 4), za[s]);
        stb(bufB, base2 + (s << 4), zb[s]);
    }
    __syncthreads();

    // ---- stage 3: block nibswap(t), RMW; write back slots 8..15 only ----
    const int base3 = (((t & 15) << 4) | (t >> 4)) << 4;
#pragma unroll
    for (int w = 0; w < 8; ++w) {
        float4 va = *reinterpret_cast<const float4*>(&bufA[SW(base3 + 2 * w)]);
        float4 vb = *reinterpret_cast<const float4*>(&bufB[SW(base3 + 2 * w)]);
        za[2 * w] = {va.x, va.y};
        za[2 * w + 1] = {va.z, va.w};
        zb[2 * w] = {vb.x, vb.y};
        zb[2 * w + 1] = {vb.z, vb.w};
    }
    dft16(za);  // za[s] = Z_a[t + 256 s]
    dft16(zb);  // zb[s] = Z_b[t + 256 s]
#pragma unroll
    for (int w = 4; w < 8; ++w) {
        *reinterpret_cast<float4*>(&bufA[SW(base3 + 2 * w)]) =
            make_float4(za[2 * w].x, za[2 * w].y, za[2 * w + 1].x, za[2 * w + 1].y);
        *reinterpret_cast<float4*>(&bufB[SW(base3 + 2 * w)]) =
            make_float4(zb[2 * w].x, zb[2 * w].y, zb[2 * w + 1].x, zb[2 * w + 1].y);
    }
    __syncthreads();

    // ---- epilogue (shared factors, both rows) ----
    float s4, c4, s1, c1;
    __sincosf((PI_F / 4096.0f) * (float)t, &s4, &c4);
    __sincosf((PI_F / 16384.0f) * (float)t, &s1, &c1);
    const cpx w4 = {c4, -s4};  // e^{-i pi t/4096}
    const cpx w1 = {c1, s1};   // {cos, sin}(pi t/16384)

    // single-k emit for both rows (t=0 self-paired line only)
    auto emit2 = [&](int s, cpx Z1a, cpx Z2a, cpx Z1b, cpx Z2b, bool writeLow) {
        const int k = t + (s << 8);
        cpx w4s = cmul(w4, cpx{C16[s], -S16[s]});
        cpx w1s = cmul(w1, cpx{C64[s], S64[s]});
        {
            cpx Ze = 0.5f * cpx{Z1a.x + Z2a.x, Z1a.y - Z2a.y};
            cpx Zo = 0.5f * cpx{Z1a.y + Z2a.y, Z2a.x - Z1a.x};
            cpx V = Ze + cmul(w4s, Zo);
            ya[8191 - k] = fmaf(V.x, w1s.x, V.y * w1s.y);
            if (writeLow) ya[k - 1] = fmaf(V.x, w1s.y, -V.y * w1s.x);
        }
        {
            cpx Ze = 0.5f * cpx{Z1b.x + Z2b.x, Z1b.y - Z2b.y};
            cpx Zo = 0.5f * cpx{Z1b.y + Z2b.y, Z2b.x - Z1b.x};
            cpx V = Ze + cmul(w4s, Zo);
            yb[8191 - k] = fmaf(V.x, w1s.x, V.y * w1s.y);
            if (writeLow) yb[k - 1] = fmaf(V.x, w1s.y, -V.y * w1s.x);
        }
    };

    // pair emit both rows: k = t+256s AND k' = 4096-k, s in [0,8)
    auto pair_emit2 = [&](int s, cpx Z1a, cpx Z2a, cpx Z1b, cpx Z2b) {
        const int k = t + (s << 8);
        cpx w4s = cmul(w4, cpx{C16[s], -S16[s]});
        cpx w1s = cmul(w1, cpx{C64[s], S64[s]});
        float cp_ = RT2O2 * (w1s.x + w1s.y);   // cos(pi/4 - phi)
        float sp_ = RT2O2 * (w1s.x - w1s.y);   // sin(pi/4 - phi)
        {
            cpx Ze = 0.5f * cpx{Z1a.x + Z2a.x, Z1a.y - Z2a.y};
            cpx Zo = 0.5f * cpx{Z1a.y + Z2a.y, Z2a.x - Z1a.x};
            cpx P = cmul(w4s, Zo);
            cpx V = Ze + P;
            cpx Vp = {Ze.x - P.x, P.y - Ze.y};  // conj(Ze - P)
            ya[8191 - k] = fmaf(V.x, w1s.x, V.y * w1s.y);
            ya[k - 1]    = fmaf(V.x, w1s.y, -V.y * w1s.x);
            ya[4095 + k] = fmaf(Vp.x, cp_, Vp.y * sp_);
            ya[4095 - k] = fmaf(Vp.x, sp_, -Vp.y * cp_);
        }
        {
            cpx Ze = 0.5f * cpx{Z1b.x + Z2b.x, Z1b.y - Z2b.y};
            cpx Zo = 0.5f * cpx{Z1b.y + Z2b.y, Z2b.x - Z1b.x};
            cpx P = cmul(w4s, Zo);
            cpx V = Ze + P;
            cpx Vp = {Ze.x - P.x, P.y - Ze.y};
            yb[8191 - k] = fmaf(V.x, w1s.x, V.y * w1s.y);
            yb[k - 1]    = fmaf(V.x, w1s.y, -V.y * w1s.x);
            yb[4095 + k] = fmaf(Vp.x, cp_, Vp.y * sp_);
            yb[4095 - k] = fmaf(Vp.x, sp_, -Vp.y * cp_);
        }
    };

    if (t == 0) {
        // self-paired set: k = 256 s; partner slot (16-s)&15
#pragma unroll
        for (int s = 0; s < 16; ++s)
            emit2(s, za[s], za[(16 - s) & 15], zb[s], zb[(16 - s) & 15], s > 0);
        ya[4095] = (za[0].x - za[0].y) * RT2O2;  // k = 4096 terms
        yb[4095] = (zb[0].x - zb[0].y) * RT2O2;
    } else if (t == 128) {
        // line pairs with itself: Z[4096-k] = own slot 15-s
#pragma unroll
        for (int s = 0; s < 8; ++s) pair_emit2(s, za[s], za[15 - s], zb[s], zb[15 - s]);
    } else {
        const int mu = 256 - t;
        const int pb = (((mu & 15) << 4) | (mu >> 4)) << 4;
        // partner slots j = 15-s for s in [0,8) -> units w = 4..7
#pragma unroll
        for (int w = 4; w < 8; ++w) {
            float4 va = *reinterpret_cast<const float4*>(&bufA[SW(pb + 2 * w)]);
            float4 vb = *reinterpret_cast<const float4*>(&bufB[SW(pb + 2 * w)]);
            pair_emit2(15 - 2 * w, za[15 - 2 * w], cpx{va.x, va.y},
                       zb[15 - 2 * w], cpx{vb.x, vb.y});          // j = 2w
            pair_emit2(14 - 2 * w, za[14 - 2 * w], cpx{va.z, va.w},
                       zb[14 - 2 * w], cpx{vb.z, vb.w});          // j = 2w+1
        }
    }
}

extern "C" void kernel_launch(void* const* d_in, const int* in_sizes, int n_in,
                              void* d_out, int out_size, void* d_ws, size_t ws_size,
                              hipStream_t stream) {
    const float* x = (const float*)d_in[0];
    float* out = (float*)d_out;
    const int rows = in_sizes[0] / 8192;  // 4096
    dst_fft_kernel<<<rows / 2, THREADS, 0, stream>>>(x, out);
}

// Round 19
// 55.204 us; speedup vs baseline: 1.2033x; 1.2033x over previous
//
#include <hip/hip_runtime.h>

#define THREADS 256
#define PI_F 3.14159265358979323846f
#define RT2O2 0.70710678118654752440f

// Complex as native 2-float vector -> packed fp32 (v_pk_add/fma_f32).
typedef float cpx __attribute__((ext_vector_type(2)));

__device__ __forceinline__ cpx cmul(cpx a, cpx b) {
    cpx r = cpx{a.x, a.x} * b;
    return r + cpx{-a.y, a.y} * cpx{b.y, b.x};
}
__device__ __forceinline__ cpx mulni(cpx a) { return cpx{a.y, -a.x}; }   // * (-i)
__device__ __forceinline__ cpx mulpi(cpx a) { return cpx{-a.y, a.x}; }   // * (+i)

// XOR swizzle on cpx index (8B units): bits [3:1] ^= (bits[6:4]^bits[10:8]).
// Bit 0 untouched -> cpx-pair (float4) contiguity preserved.
__device__ __forceinline__ int SW(int i) { return i ^ ((((i >> 4) ^ (i >> 8)) & 7) << 1); }

__device__ __forceinline__ cpx ldb(const cpx* b, int i) { return b[SW(i)]; }
__device__ __forceinline__ void stb(cpx* b, int i, cpx v) { b[SW(i)] = v; }

// cos/sin(pi*s/16) and cos/sin(pi*s/64), s = 0..15 (compile-time folded).
constexpr float C16[16] = {
    1.f, 0.98078528040323044f, 0.92387953251128674f, 0.83146961230254524f,
    RT2O2, 0.55557023301960222f, 0.38268343236508978f, 0.19509032201612827f,
    0.f, -0.19509032201612827f, -0.38268343236508978f, -0.55557023301960222f,
    -RT2O2, -0.83146961230254524f, -0.92387953251128674f, -0.98078528040323044f};
constexpr float S16[16] = {
    0.f, 0.19509032201612827f, 0.38268343236508978f, 0.55557023301960222f,
    RT2O2, 0.83146961230254524f, 0.92387953251128674f, 0.98078528040323044f,
    1.f, 0.98078528040323044f, 0.92387953251128674f, 0.83146961230254524f,
    RT2O2, 0.55557023301960222f, 0.38268343236508978f, 0.19509032201612827f};
constexpr float C64[16] = {
    1.f, 0.99879545620517239f, 0.99518472667219693f, 0.98917650996478101f,
    0.98078528040323044f, 0.97003125319454397f, 0.95694033573220886f, 0.94154406518302081f,
    0.92387953251128674f, 0.90398929312344334f, 0.88192126434835503f, 0.85772861000027212f,
    0.83146961230254524f, 0.80320753148064494f, 0.77301045336273699f, 0.74095112535495911f};
constexpr float S64[16] = {
    0.f, 0.04906767432741801f, 0.09801714032956060f, 0.14673047445536175f,
    0.19509032201612827f, 0.24298017990326390f, 0.29028467725446233f, 0.33688985339222005f,
    0.38268343236508978f, 0.42755509343028208f, 0.47139673682599764f, 0.51410274419322166f,
    0.55557023301960222f, 0.59569930449243336f, 0.63439328416364549f, 0.67155895484701833f};

// In-place 16-point DFT, natural order in/out: z[s] = sum_n z[n] W16^{ns}
__device__ __forceinline__ void dft16(cpx* z) {
    cpx t[4][4];
#pragma unroll
    for (int n0 = 0; n0 < 4; ++n0) {
        cpx a = z[n0], b = z[4 + n0], c = z[8 + n0], d = z[12 + n0];
        cpx apc = a + c, amc = a - c, bpd = b + d, bmd = b - d;
        t[n0][0] = apc + bpd;
        t[n0][1] = amc + mulni(bmd);
        t[n0][2] = apc - bpd;
        t[n0][3] = amc + mulpi(bmd);
    }
    const cpx W1 = {0.92387953251128674f, -0.38268343236508978f};
    const cpx W2 = {RT2O2, -RT2O2};
    const cpx W3 = {0.38268343236508978f, -0.92387953251128674f};
    const cpx W6 = {-RT2O2, -RT2O2};
    const cpx W9 = {-0.92387953251128674f, 0.38268343236508978f};
    t[1][1] = cmul(t[1][1], W1); t[1][2] = cmul(t[1][2], W2); t[1][3] = cmul(t[1][3], W3);
    t[2][1] = cmul(t[2][1], W2); t[2][2] = mulni(t[2][2]);    t[2][3] = cmul(t[2][3], W6);
    t[3][1] = cmul(t[3][1], W3); t[3][2] = cmul(t[3][2], W6); t[3][3] = cmul(t[3][3], W9);
#pragma unroll
    for (int s0 = 0; s0 < 4; ++s0) {
        cpx a = t[0][s0], b = t[1][s0], c = t[2][s0], d = t[3][s0];
        cpx apc = a + c, amc = a - c, bpd = b + d, bmd = b - d;
        z[s0]      = apc + bpd;
        z[s0 + 4]  = amc + mulni(bmd);
        z[s0 + 8]  = apc - bpd;
        z[s0 + 12] = amc + mulpi(bmd);
    }
}

// z[s] *= w1^s, s=1..15; powers via squaring tree (dep depth ~4, not 15).
__device__ __forceinline__ void twiddle16(cpx* z, float theta) {
    float s_, c_;
    __sincosf(theta, &s_, &c_);
    cpx w1 = {c_, s_};
    cpx w2 = cmul(w1, w1), w3 = cmul(w1, w2), w4 = cmul(w2, w2);
    cpx w5 = cmul(w1, w4), w6 = cmul(w2, w4), w7 = cmul(w3, w4), w8 = cmul(w4, w4);
    cpx w9 = cmul(w1, w8), w10 = cmul(w2, w8), w11 = cmul(w3, w8), w12 = cmul(w4, w8);
    cpx w13 = cmul(w5, w8), w14 = cmul(w6, w8), w15 = cmul(w7, w8);
    z[1] = cmul(z[1], w1);   z[2] = cmul(z[2], w2);   z[3] = cmul(z[3], w3);
    z[4] = cmul(z[4], w4);   z[5] = cmul(z[5], w5);   z[6] = cmul(z[6], w6);
    z[7] = cmul(z[7], w7);   z[8] = cmul(z[8], w8);   z[9] = cmul(z[9], w9);
    z[10] = cmul(z[10], w10); z[11] = cmul(z[11], w11); z[12] = cmul(z[12], w12);
    z[13] = cmul(z[13], w13); z[14] = cmul(z[14], w14); z[15] = cmul(z[15], w15);
}

// One row per block (R14 structure — best measured across 18 rounds).
// DST-II via N/2=4096 complex FFT (radices 16,16,16):
//   v = Makhoul(sign*x); z[m] = v[2m] + i*v[2m+1]; Z = FFT_4096(z)
//   V[k] = Ze[k] + e^{-i pi k/4096} Zo[k]; out[8191-k] = Re(V[k] e^{-i pi k/16384})
// Pair-folded epilogue: emit(k) and emit(4096-k) share (Z1,Z2):
//   Ze' = conj(Ze), Zo' = conj(Zo), w4s' = -conj(w4s)  =>  V' = conj(Ze - P),
//   P = w4s*Zo (already computed for V = Ze + P); phi' = pi/4 - phi =>
//   {c',s'} = {r(c+s), r(c-s)}, r = sqrt(2)/2.
// Each thread t handles s in [0,8) and emits 4 outputs per s. Only slots
// 8..15 of each stage-3 line are read by partner threads -> write back half.
// t=0: self-paired line (full loop + Nyquist). t=128: pairs in own regs.
__global__ __launch_bounds__(THREADS) void dst_fft_kernel(const float* __restrict__ x,
                                                          float* __restrict__ out) {
    __shared__ __align__(16) cpx buf[4096];  // 32 KiB

    const int row = blockIdx.x;
    const float* __restrict__ xr = x + (size_t)row * 8192;
    float* __restrict__ yr = out + (size_t)row * 8192;
    const int t = threadIdx.x;

    cpx z[16];

    // ---- load in stage-1 butterfly order: m = t + 256u ----
#pragma unroll
    for (int u = 0; u < 8; ++u) {
        float4 f = *reinterpret_cast<const float4*>(xr + 4 * t + 1024 * u);
        z[u] = {f.x, f.z};
    }
#pragma unroll
    for (int u = 8; u < 16; ++u) {
        float4 f = *reinterpret_cast<const float4*>(xr + (16380 - 4 * t - 1024 * u));
        z[u] = {-f.w, -f.y};
    }

    // ---- stage 1: radix-16, stride 256 ----
    dft16(z);
    twiddle16(z, (-2.0f * PI_F / 4096.0f) * (float)t);
#pragma unroll
    for (int s = 0; s < 16; ++s) stb(buf, t + (s << 8), z[s]);
    __syncthreads();

    // ---- stage 2: 16 sub-FFTs of length 256, stride 16 (in-place per thread) ----
    const int base2 = ((t >> 4) << 8) + (t & 15);
#pragma unroll
    for (int s = 0; s < 16; ++s) z[s] = ldb(buf, base2 + (s << 4));
    dft16(z);
    twiddle16(z, (-2.0f * PI_F / 256.0f) * (float)(t & 15));
#pragma unroll
    for (int s = 0; s < 16; ++s) stb(buf, base2 + (s << 4), z[s]);
    __syncthreads();

    // ---- stage 3: block b = nibswap(t), in-place RMW; write back slots 8..15 ----
    const int base3 = (((t & 15) << 4) | (t >> 4)) << 4;
#pragma unroll
    for (int w = 0; w < 8; ++w) {
        float4 v = *reinterpret_cast<const float4*>(&buf[SW(base3 + 2 * w)]);
        z[2 * w] = {v.x, v.y};
        z[2 * w + 1] = {v.z, v.w};
    }
    dft16(z);  // z[s] = Z[t + 256 s], kept in registers
#pragma unroll
    for (int w = 4; w < 8; ++w) {  // only slots 8..15 are read by partners
        *reinterpret_cast<float4*>(&buf[SW(base3 + 2 * w)]) =
            make_float4(z[2 * w].x, z[2 * w].y, z[2 * w + 1].x, z[2 * w + 1].y);
    }
    __syncthreads();

    // ---- epilogue ----
    float s4, c4, s1, c1;
    __sincosf((PI_F / 4096.0f) * (float)t, &s4, &c4);
    __sincosf((PI_F / 16384.0f) * (float)t, &s1, &c1);
    const cpx w4 = {c4, -s4};  // e^{-i pi t/4096}
    const cpx w1 = {c1, s1};   // {cos, sin}(pi t/16384)

    // single-k emit (t=0 self-paired line only)
    auto emit = [&](int s, cpx Z1, cpx Z2, bool writeLow) {
        const int k = t + (s << 8);
        cpx Ze = 0.5f * cpx{Z1.x + Z2.x, Z1.y - Z2.y};
        cpx Zo = 0.5f * cpx{Z1.y + Z2.y, Z2.x - Z1.x};
        cpx w4s = cmul(w4, cpx{C16[s], -S16[s]});
        cpx w1s = cmul(w1, cpx{C64[s], S64[s]});
        cpx V = Ze + cmul(w4s, Zo);
        yr[8191 - k] = fmaf(V.x, w1s.x, V.y * w1s.y);
        if (writeLow) yr[k - 1] = fmaf(V.x, w1s.y, -V.y * w1s.x);
    };

    // pair emit: outputs for k = t+256s AND k' = 4096-k, s in [0,8)
    auto pair_emit = [&](int s, cpx Z1, cpx Z2) {
        const int k = t + (s << 8);
        cpx Ze = 0.5f * cpx{Z1.x + Z2.x, Z1.y - Z2.y};
        cpx Zo = 0.5f * cpx{Z1.y + Z2.y, Z2.x - Z1.x};
        cpx w4s = cmul(w4, cpx{C16[s], -S16[s]});
        cpx w1s = cmul(w1, cpx{C64[s], S64[s]});
        cpx P = cmul(w4s, Zo);
        cpx V = Ze + P;
        cpx Vp = {Ze.x - P.x, P.y - Ze.y};  // conj(Ze - P)
        yr[8191 - k] = fmaf(V.x, w1s.x, V.y * w1s.y);
        yr[k - 1]    = fmaf(V.x, w1s.y, -V.y * w1s.x);
        float cp_ = RT2O2 * (w1s.x + w1s.y);   // cos(pi/4 - phi)
        float sp_ = RT2O2 * (w1s.x - w1s.y);   // sin(pi/4 - phi)
        yr[4095 + k] = fmaf(Vp.x, cp_, Vp.y * sp_);
        yr[4095 - k] = fmaf(Vp.x, sp_, -Vp.y * cp_);
    };

    if (t == 0) {
        // self-paired set: k = 256 s; partner slot (16-s)&15
#pragma unroll
        for (int s = 0; s < 16; ++s) emit(s, z[s], z[(16 - s) & 15], s > 0);
        yr[4095] = (z[0].x - z[0].y) * RT2O2;  // k = 4096 term
    } else if (t == 128) {
        // line pairs with itself: Z[4096-k] = own slot 15-s
#pragma unroll
        for (int s = 0; s < 8; ++s) pair_emit(s, z[s], z[15 - s]);
    } else {
        const int mu = 256 - t;
        const int pb = (((mu & 15) << 4) | (mu >> 4)) << 4;
        // partner slots j = 15-s for s in [0,8) -> units w = 4..7
#pragma unroll
        for (int w = 4; w < 8; ++w) {
            float4 v = *reinterpret_cast<const float4*>(&buf[SW(pb + 2 * w)]);
            pair_emit(15 - 2 * w, z[15 - 2 * w], cpx{v.x, v.y});  // j = 2w
            pair_emit(14 - 2 * w, z[14 - 2 * w], cpx{v.z, v.w});  // j = 2w+1
        }
    }
}

extern "C" void kernel_launch(void* const* d_in, const int* in_sizes, int n_in,
                              void* d_out, int out_size, void* d_ws, size_t ws_size,
                              hipStream_t stream) {
    const float* x = (const float*)d_in[0];
    float* out = (float*)d_out;
    const int rows = in_sizes[0] / 8192;  // 4096
    dst_fft_kernel<<<rows, THREADS, 0, stream>>>(x, out);
}